// Round 1
// baseline (213.109 us; speedup 1.0000x reference)
//
#include <hip/hip_runtime.h>
#include <hip/hip_bf16.h>

#define NH 4096          // rows per input
#define NT 8192          // 2*NH
#define D  256
#define BM 128           // tile M = N
#define BK 64            // K chunk

typedef float f32x4 __attribute__((ext_vector_type(4)));
typedef int   i32x4 __attribute__((ext_vector_type(4)));

typedef __attribute__((address_space(1))) const void gas_t;
typedef __attribute__((address_space(3))) void las_t;

__device__ inline void mfma_bf16(f32x4& d, i32x4 a, i32x4 b) {
  asm("v_mfma_f32_16x16x32_bf16 %0, %1, %2, %0" : "+v"(d) : "v"(a), "v"(b));
}

// ---------------- K0: zero accumulators in ws (ws is re-poisoned 0xAA) ----
__global__ void k_zero(double* S1, double* acc, double* svec) {
  int t = threadIdx.x;
  if (t == 0) { *S1 = 0.0; *acc = 0.0; }
  if (t < 256) svec[t] = 0.0;
}

// ---------------- K1: per-row sq, bf16 convert, S1 ------------------------
__global__ void k_rows(const float* __restrict__ src, const float* __restrict__ tgt,
                       unsigned short* __restrict__ Xb, float* __restrict__ sq,
                       double* __restrict__ S1) {
  int wid = threadIdx.x >> 6, lane = threadIdx.x & 63;
  int r = blockIdx.x * 4 + wid;
  const float* row = (r < NH) ? (src + (size_t)r * D) : (tgt + (size_t)(r - NH) * D);
  float4 v = ((const float4*)row)[lane];
  float sp = v.x * v.x + v.y * v.y + v.z * v.z + v.w * v.w;
  ushort4 u;
  u.x = __builtin_bit_cast(unsigned short, __float2bfloat16(v.x));
  u.y = __builtin_bit_cast(unsigned short, __float2bfloat16(v.y));
  u.z = __builtin_bit_cast(unsigned short, __float2bfloat16(v.z));
  u.w = __builtin_bit_cast(unsigned short, __float2bfloat16(v.w));
  ((ushort4*)(Xb + (size_t)r * D))[lane] = u;
  #pragma unroll
  for (int off = 32; off; off >>= 1) sp += __shfl_xor(sp, off, 64);
  if (lane == 0) { sq[r] = sp; atomicAdd(S1, (double)sp); }
}

// ---------------- K2: column sums (for ||sum x||^2) -----------------------
__global__ void k_cols(const float* __restrict__ src, const float* __restrict__ tgt,
                       double* __restrict__ svec) {
  int t = threadIdx.x, b = blockIdx.x;   // 256 blocks x 32 rows
  const float* base = (b < 128) ? (src + (size_t)b * 32 * D)
                                : (tgt + (size_t)(b - 128) * 32 * D);
  float a = 0.f;
  #pragma unroll 4
  for (int r = 0; r < 32; ++r) a += base[(size_t)r * D + t];
  atomicAdd(&svec[t], (double)a);
}

// ---------------- K3: bandwidth -> single exp2 scale ----------------------
__global__ void k_bw(const double* __restrict__ S1, const double* __restrict__ svec,
                     float* __restrict__ nk) {
  __shared__ double red[256];
  int t = threadIdx.x;
  double s = svec[t];
  red[t] = s * s;
  __syncthreads();
  for (int off = 128; off; off >>= 1) {
    if (t < off) red[t] += red[t + off];
    __syncthreads();
  }
  if (t == 0) {
    double n = (double)NT;
    double l2sum = 2.0 * n * (*S1) - 2.0 * red[0];
    double bw = l2sum / (n * n - n) / 4.0;       // / KERNEL_MUL^(KERNEL_NUM//2)
    const double LOG2E = 1.4426950408889634;
    // t16 = exp(-L2/(16 b)) = 2^(L2 * nk); K = t16 + t16^2 + t16^4 + t16^8 + t16^16
    nk[0] = (float)(-LOG2E / (16.0 * bw));
  }
}

// ---------------- K4: fused Gram + RBF + signed reduce --------------------
__global__ __launch_bounds__(256) void k_main(const unsigned short* __restrict__ Xb,
                                              const float* __restrict__ sq,
                                              const float* __restrict__ nk,
                                              double* __restrict__ acc_d) {
  const int ti = blockIdx.y, tj = blockIdx.x;
  if (tj < ti) return;                       // triangular: K is symmetric

  __shared__ __align__(16) unsigned short As[BM * BK];  // XOR-swizzled layout
  __shared__ __align__(16) unsigned short Bs[BM * BK];
  __shared__ float sqa[BM], sqb[BM];
  __shared__ double red[256];

  const int tid = threadIdx.x;
  const int wid = tid >> 6, lane = tid & 63;
  const int rowbase = ti * BM, colbase = tj * BM;

  if (tid < 128) sqa[tid] = sq[rowbase + tid];
  else           sqb[tid - 128] = sq[colbase + tid - 128];

  const float nkr = nk[0];

  f32x4 acc[4][4];
  #pragma unroll
  for (int m = 0; m < 4; ++m)
    #pragma unroll
    for (int n = 0; n < 4; ++n) acc[m][n] = (f32x4){0.f, 0.f, 0.f, 0.f};

  const int wr = (wid >> 1) * 64;            // wave's 64x64 sub-tile
  const int wc = (wid & 1) * 64;

  for (int c = 0; c < 4; ++c) {              // K chunks of 64 (D=256)
    __syncthreads();                         // protect LDS from prior reads
    #pragma unroll
    for (int it = 0; it < 4; ++it) {
      int s = it * 256 + tid;                // 16B slot
      int r = s >> 3, gl = s & 7;
      int gsrc = gl ^ (r & 7);               // inverse-swizzled global source
      const unsigned short* gA = Xb + (size_t)(rowbase + r) * D + c * BK + gsrc * 8;
      const unsigned short* gB = Xb + (size_t)(colbase + r) * D + c * BK + gsrc * 8;
      __builtin_amdgcn_global_load_lds((gas_t*)gA, (las_t*)((char*)As + s * 16), 16, 0, 0);
      __builtin_amdgcn_global_load_lds((gas_t*)gB, (las_t*)((char*)Bs + s * 16), 16, 0, 0);
    }
    asm volatile("s_waitcnt vmcnt(0)" ::: "memory");
    __syncthreads();
    #pragma unroll
    for (int h = 0; h < 2; ++h) {            // two k=32 sub-steps
      const int kg = (h * 32 + ((lane >> 4) * 8)) >> 3;
      i32x4 af[4], bf[4];
      #pragma unroll
      for (int m = 0; m < 4; ++m) {
        int ra = wr + m * 16 + (lane & 15);
        af[m] = *(const i32x4*)((const char*)As + ra * 128 + ((kg ^ (ra & 7)) << 4));
        int rb = wc + m * 16 + (lane & 15);
        bf[m] = *(const i32x4*)((const char*)Bs + rb * 128 + ((kg ^ (rb & 7)) << 4));
      }
      #pragma unroll
      for (int m = 0; m < 4; ++m)
        #pragma unroll
        for (int n = 0; n < 4; ++n)
          mfma_bf16(acc[m][n], af[m], bf[n]);
    }
  }

  // epilogue: L2 -> 5-bandwidth RBF via one exp + squaring chain
  float ts = 0.f;
  #pragma unroll
  for (int m = 0; m < 4; ++m) {
    float sa[4];
    #pragma unroll
    for (int q = 0; q < 4; ++q) sa[q] = sqa[wr + m * 16 + ((lane >> 4) << 2) + q];
    #pragma unroll
    for (int n = 0; n < 4; ++n) {
      float sb = sqb[wc + n * 16 + (lane & 15)];
      #pragma unroll
      for (int q = 0; q < 4; ++q) {
        float g  = acc[m][n][q];
        float l2 = fmaf(-2.f, g, sa[q] + sb);
        float t1  = __builtin_amdgcn_exp2f(l2 * nkr);  // exp(-L2/(16b))
        float t2  = t1 * t1;
        float t4  = t2 * t2;
        float t8  = t4 * t4;
        float t16 = t8 * t8;
        ts += t1 + t2 + t4 + t8 + t16;
      }
    }
  }

  red[tid] = (double)ts;
  __syncthreads();
  for (int off = 128; off; off >>= 1) {
    if (tid < off) red[tid] += red[tid + off];
    __syncthreads();
  }
  if (tid == 0) {
    double w = (ti == tj) ? 1.0 : 2.0;                       // symmetry weight
    double sgn = ((ti < 32) == (tj < 32)) ? 1.0 : -1.0;      // block sign
    atomicAdd(acc_d, sgn * w * red[0]);
  }
}

// ---------------- K5: finalize --------------------------------------------
__global__ void k_fin(const double* __restrict__ acc_d, float* __restrict__ out) {
  out[0] = (float)(*acc_d * (1.0 / ((double)NH * (double)NH)));
}

extern "C" void kernel_launch(void* const* d_in, const int* in_sizes, int n_in,
                              void* d_out, int out_size, void* d_ws, size_t ws_size,
                              hipStream_t stream) {
  const float* src = (const float*)d_in[0];
  const float* tgt = (const float*)d_in[1];
  char* ws = (char*)d_ws;
  double* S1   = (double*)(ws + 0);
  double* acc  = (double*)(ws + 8);
  float*  nk   = (float*)(ws + 16);
  double* svec = (double*)(ws + 64);
  float*  sqv  = (float*)(ws + 4096);
  unsigned short* Xb = (unsigned short*)(ws + 65536);
  float* out = (float*)d_out;

  k_zero<<<1, 256, 0, stream>>>(S1, acc, svec);
  k_rows<<<NT / 4, 256, 0, stream>>>(src, tgt, Xb, sqv, S1);
  k_cols<<<256, 256, 0, stream>>>(src, tgt, svec);
  k_bw<<<1, 256, 0, stream>>>(S1, svec, nk);
  dim3 grid(NT / BM, NT / BM);
  k_main<<<grid, 256, 0, stream>>>(Xb, sqv, nk, acc);
  k_fin<<<1, 1, 0, stream>>>(acc, out);
}

// Round 2
// 121.513 us; speedup vs baseline: 1.7538x; 1.7538x over previous
//
#include <hip/hip_runtime.h>
#include <hip/hip_bf16.h>

#define NH 4096          // rows per input
#define NT 8192          // 2*NH
#define D  256
#define BM 128           // tile M = N
#define BK 64            // K chunk

typedef float f32x4 __attribute__((ext_vector_type(4)));
typedef int   i32x4 __attribute__((ext_vector_type(4)));

typedef __attribute__((address_space(1))) const void gas_t;
typedef __attribute__((address_space(3))) void las_t;

__device__ inline void mfma_bf16(f32x4& d, i32x4 a, i32x4 b) {
  asm("v_mfma_f32_16x16x32_bf16 %0, %1, %2, %0" : "+v"(d) : "v"(a), "v"(b));
}

// ---------------- K1: per-row sq + bf16 convert (NO atomics) --------------
__global__ void k_rows(const float* __restrict__ src, const float* __restrict__ tgt,
                       unsigned short* __restrict__ Xb, float* __restrict__ sq) {
  int wid = threadIdx.x >> 6, lane = threadIdx.x & 63;
  int r = blockIdx.x * 4 + wid;
  const float* row = (r < NH) ? (src + (size_t)r * D) : (tgt + (size_t)(r - NH) * D);
  float4 v = ((const float4*)row)[lane];
  float sp = v.x * v.x + v.y * v.y + v.z * v.z + v.w * v.w;
  ushort4 u;
  u.x = __builtin_bit_cast(unsigned short, __float2bfloat16(v.x));
  u.y = __builtin_bit_cast(unsigned short, __float2bfloat16(v.y));
  u.z = __builtin_bit_cast(unsigned short, __float2bfloat16(v.z));
  u.w = __builtin_bit_cast(unsigned short, __float2bfloat16(v.w));
  ((ushort4*)(Xb + (size_t)r * D))[lane] = u;
  #pragma unroll
  for (int off = 32; off; off >>= 1) sp += __shfl_xor(sp, off, 64);
  if (lane == 0) sq[r] = sp;
}

// ---------------- K2: per-block partial column sums (NO atomics) ----------
__global__ void k_cols(const float* __restrict__ src, const float* __restrict__ tgt,
                       float* __restrict__ colpart) {
  int t = threadIdx.x, b = blockIdx.x;   // 256 blocks x 32 rows
  const float* base = (b < 128) ? (src + (size_t)b * 32 * D)
                                : (tgt + (size_t)(b - 128) * 32 * D);
  float a = 0.f;
  #pragma unroll 4
  for (int r = 0; r < 32; ++r) a += base[(size_t)r * D + t];
  colpart[(size_t)b * 256 + t] = a;
}

// ---------------- K3: reduce sq + colparts -> bandwidth scale; zero acc ---
__global__ void k_bw(const float* __restrict__ sqv, const float* __restrict__ colpart,
                     float* __restrict__ nk, double* __restrict__ acc) {
  __shared__ double red[256];
  int t = threadIdx.x;

  double ssum = 0.0;                       // sum of per-row squared norms
  for (int i = t; i < NT; i += 256) ssum += (double)sqv[i];
  red[t] = ssum;
  __syncthreads();
  for (int off = 128; off; off >>= 1) {
    if (t < off) red[t] += red[t + off];
    __syncthreads();
  }
  double S1 = red[0];
  __syncthreads();

  double cs = 0.0;                         // column sum -> ||sum x||^2
  for (int b = 0; b < 256; ++b) cs += (double)colpart[(size_t)b * 256 + t];
  red[t] = cs * cs;
  __syncthreads();
  for (int off = 128; off; off >>= 1) {
    if (t < off) red[t] += red[t + off];
    __syncthreads();
  }
  if (t == 0) {
    double n = (double)NT;
    double l2sum = 2.0 * n * S1 - 2.0 * red[0];
    double bw = l2sum / (n * n - n) / 4.0;       // / KERNEL_MUL^(KERNEL_NUM//2)
    const double LOG2E = 1.4426950408889634;
    // t16 = exp(-L2/(16 b)) = 2^(L2 * nk); K = t16 + t16^2 + t16^4 + t16^8 + t16^16
    nk[0] = (float)(-LOG2E / (16.0 * bw));
    *acc = 0.0;
  }
}

// ---------------- K4: fused Gram + RBF + signed reduce --------------------
__global__ __launch_bounds__(256) void k_main(const unsigned short* __restrict__ Xb,
                                              const float* __restrict__ sq,
                                              const float* __restrict__ nk,
                                              double* __restrict__ acc_d) {
  const int ti = blockIdx.y, tj = blockIdx.x;
  if (tj < ti) return;                       // triangular: K is symmetric

  __shared__ __align__(16) unsigned short As[BM * BK];  // XOR-swizzled layout
  __shared__ __align__(16) unsigned short Bs[BM * BK];
  __shared__ float sqa[BM], sqb[BM];
  __shared__ double red[256];

  const int tid = threadIdx.x;
  const int wid = tid >> 6, lane = tid & 63;
  const int rowbase = ti * BM, colbase = tj * BM;

  if (tid < 128) sqa[tid] = sq[rowbase + tid];
  else           sqb[tid - 128] = sq[colbase + tid - 128];

  const float nkr = nk[0];

  f32x4 acc[4][4];
  #pragma unroll
  for (int m = 0; m < 4; ++m)
    #pragma unroll
    for (int n = 0; n < 4; ++n) acc[m][n] = (f32x4){0.f, 0.f, 0.f, 0.f};

  const int wr = (wid >> 1) * 64;            // wave's 64x64 sub-tile
  const int wc = (wid & 1) * 64;

  for (int c = 0; c < 4; ++c) {              // K chunks of 64 (D=256)
    __syncthreads();                         // protect LDS from prior reads
    #pragma unroll
    for (int it = 0; it < 4; ++it) {
      int s = it * 256 + tid;                // 16B slot
      int r = s >> 3, gl = s & 7;
      int gsrc = gl ^ (r & 7);               // inverse-swizzled global source
      const unsigned short* gA = Xb + (size_t)(rowbase + r) * D + c * BK + gsrc * 8;
      const unsigned short* gB = Xb + (size_t)(colbase + r) * D + c * BK + gsrc * 8;
      __builtin_amdgcn_global_load_lds((gas_t*)gA, (las_t*)((char*)As + s * 16), 16, 0, 0);
      __builtin_amdgcn_global_load_lds((gas_t*)gB, (las_t*)((char*)Bs + s * 16), 16, 0, 0);
    }
    asm volatile("s_waitcnt vmcnt(0)" ::: "memory");
    __syncthreads();
    #pragma unroll
    for (int h = 0; h < 2; ++h) {            // two k=32 sub-steps
      const int kg = (h * 32 + ((lane >> 4) * 8)) >> 3;
      i32x4 af[4], bf[4];
      #pragma unroll
      for (int m = 0; m < 4; ++m) {
        int ra = wr + m * 16 + (lane & 15);
        af[m] = *(const i32x4*)((const char*)As + ra * 128 + ((kg ^ (ra & 7)) << 4));
        int rb = wc + m * 16 + (lane & 15);
        bf[m] = *(const i32x4*)((const char*)Bs + rb * 128 + ((kg ^ (rb & 7)) << 4));
      }
      #pragma unroll
      for (int m = 0; m < 4; ++m)
        #pragma unroll
        for (int n = 0; n < 4; ++n)
          mfma_bf16(acc[m][n], af[m], bf[n]);
    }
  }

  // epilogue: L2 -> 5-bandwidth RBF via one exp + squaring chain
  float ts = 0.f;
  #pragma unroll
  for (int m = 0; m < 4; ++m) {
    float sa[4];
    #pragma unroll
    for (int q = 0; q < 4; ++q) sa[q] = sqa[wr + m * 16 + ((lane >> 4) << 2) + q];
    #pragma unroll
    for (int n = 0; n < 4; ++n) {
      float sb = sqb[wc + n * 16 + (lane & 15)];
      #pragma unroll
      for (int q = 0; q < 4; ++q) {
        float g  = acc[m][n][q];
        float l2 = fmaf(-2.f, g, sa[q] + sb);
        float t1  = __builtin_amdgcn_exp2f(l2 * nkr);  // exp(-L2/(16b))
        float t2  = t1 * t1;
        float t4  = t2 * t2;
        float t8  = t4 * t4;
        float t16 = t8 * t8;
        ts += t1 + t2 + t4 + t8 + t16;
      }
    }
  }

  red[tid] = (double)ts;
  __syncthreads();
  for (int off = 128; off; off >>= 1) {
    if (tid < off) red[tid] += red[tid + off];
    __syncthreads();
  }
  if (tid == 0) {
    double w = (ti == tj) ? 1.0 : 2.0;                       // symmetry weight
    double sgn = ((ti < 32) == (tj < 32)) ? 1.0 : -1.0;      // block sign
    atomicAdd(acc_d, sgn * w * red[0]);
  }
}

// ---------------- K5: finalize --------------------------------------------
__global__ void k_fin(const double* __restrict__ acc_d, float* __restrict__ out) {
  out[0] = (float)(*acc_d * (1.0 / ((double)NH * (double)NH)));
}

extern "C" void kernel_launch(void* const* d_in, const int* in_sizes, int n_in,
                              void* d_out, int out_size, void* d_ws, size_t ws_size,
                              hipStream_t stream) {
  const float* src = (const float*)d_in[0];
  const float* tgt = (const float*)d_in[1];
  char* ws = (char*)d_ws;
  double* acc  = (double*)(ws + 0);
  float*  nk   = (float*)(ws + 16);
  float*  sqv  = (float*)(ws + 4096);                 // 32 KB
  float*  colpart = (float*)(ws + 40960);             // 256 KB
  unsigned short* Xb = (unsigned short*)(ws + 327680); // 4 MB
  float* out = (float*)d_out;

  k_rows<<<NT / 4, 256, 0, stream>>>(src, tgt, Xb, sqv);
  k_cols<<<256, 256, 0, stream>>>(src, tgt, colpart);
  k_bw<<<1, 256, 0, stream>>>(sqv, colpart, nk, acc);
  dim3 grid(NT / BM, NT / BM);
  k_main<<<grid, 256, 0, stream>>>(Xb, sqv, nk, acc);
  k_fin<<<1, 1, 0, stream>>>(acc, out);
}